// Round 11
// baseline (484.676 us; speedup 1.0000x reference)
//
#include <hip/hip_runtime.h>
#include <hip/hip_bf16.h>

using bf16 = __hip_bfloat16;

typedef __attribute__((ext_vector_type(4))) float f32x4;
typedef __attribute__((ext_vector_type(8))) short short8;

typedef const void __attribute__((address_space(1)))* gas1_t;
typedef void __attribute__((address_space(3)))* las3_t;
#define GLDS(gp, lp) __builtin_amdgcn_global_load_lds((gas1_t)(gp), (las3_t)(lp), 16, 0, 0)

__device__ inline short f2bfbits(float f) {
  union { bf16 h; short s; } u;
  u.h = __float2bfloat16(f);
  return u.s;
}
__device__ inline float bf2f(short u) {
  unsigned x = ((unsigned)(unsigned short)u) << 16;
  float f; __builtin_memcpy(&f, &x, 4); return f;
}

__device__ inline void store_out(float* C, size_t idx, float v) { C[idx] = v; }
__device__ inline void store_out(bf16* C, size_t idx, float v) { C[idx] = __float2bfloat16(v); }

// ---------------------------------------------------------------------------
// 256x256 tile GEMM, BK=32, 512 thr = 8 waves (2M x 4N); 3-ring LDS + counted
// vmcnt(4) (round-10 schedule, unchanged). NEW: XCC-aware persistent tile
// claiming — 8 per-XCD atomic queues; each queue owns an operand-locality
// slab; blocks read their PHYSICAL XCD via s_getreg(HW_REG_XCC_ID) (m09),
// claim own queue first, steal when empty (exact-once, any dispatch map).
// MODE 0: QKproj (8 bx x 64 by): queue q owns by in [q*8,q*8+8), bx-minor.
// MODE 1: causal S, 544 tri-tiles (z-major): queue q owns 68 consecutive.
// MODE 2: PV (4 bx x 16 by x 4 z): queue q owns 32 tiles in balanced pairs
//         (by, 15-by) => equal causal work per queue.
// MODE 3: Vproj (64 bx x 4 by): queue q owns bx in [q*8,q*8+8), by-minor.
// ---------------------------------------------------------------------------
template<typename TOUT, int MODE>
__global__ __launch_bounds__(512, 2) void gemm256(
    const short* __restrict__ A, int lda, size_t sAz,
    const short* __restrict__ B, int ldb, size_t sBz,
    TOUT* __restrict__ C, int ldc, size_t sCz,
    int K, float scale, int* __restrict__ qctr)
{
  constexpr int QSZ = (MODE == 0) ? 64 : (MODE == 1) ? 68 : 32;

  __shared__ short As[3][256 * 32];
  __shared__ short Bs[3][256 * 32];
  __shared__ int s_tile;

  int xcc;
  asm volatile("s_getreg_b32 %0, hwreg(HW_REG_XCC_ID)" : "=s"(xcc));
  xcc &= 7;

  const int t = threadIdx.x;
  const int lane = t & 63;
  const int wave = t >> 6;
  const int wm = wave >> 2;                 // 0..1 (128-row half)
  const int wn = wave & 3;                  // 0..3 (64-col slice)
  const int fr = lane & 15, kh = lane >> 4;
  const int koff = ((kh ^ ((fr >> 1) & 3)) << 3);   // swizzled 8-short chunk

  // staging source precompute (chunk-XOR pre-swizzled global column)
  int srow[2], scol[2];
  #pragma unroll
  for (int j = 0; j < 2; j++) {
    int e = j * 512 + t;
    srow[j] = e >> 2;
    scol[j] = (((e & 3) ^ ((e >> 3) & 3)) << 3);
  }
  const int arow = wm * 128 + fr;
  const int brow = wn * 64 + fr;

  for (;;) {
    if (t == 0) {
      int tile = -1;
      #pragma unroll
      for (int k = 0; k < 8; k++) {
        int q = (xcc + k) & 7;
        int v = atomicAdd(&qctr[q], 1);
        if (v < QSZ) { tile = q * QSZ + v; break; }
      }
      s_tile = tile;
    }
    __syncthreads();
    const int tile = s_tile;
    if (tile < 0) return;

    // ---- decode tile -> (bx, by, z) ----
    int bx, by, z;
    if constexpr (MODE == 0) {
      const int q = tile / QSZ, v = tile % QSZ;
      by = q * 8 + (v >> 3); bx = v & 7; z = 0;
    } else if constexpr (MODE == 1) {
      z = tile / 136;
      const int r = tile % 136;
      by = (int)((__builtin_sqrtf(8.f * (float)r + 1.f) - 1.f) * 0.5f);
      if (((by * (by + 1)) >> 1) > r) by--;
      else if ((((by + 1) * (by + 2)) >> 1) <= r) by++;
      bx = r - ((by * (by + 1)) >> 1);
    } else if constexpr (MODE == 2) {
      z = tile >> 6;
      const int s = tile & 63, pr = s >> 3, k = s & 7;
      by = (k < 4) ? pr : 15 - pr;
      bx = k & 3;
    } else {
      const int q = tile / QSZ, v = tile % QSZ;
      bx = q * 8 + (v >> 2); by = v & 3; z = 0;
    }
    const int tri_by = (by * (by + 1)) >> 1;

    const short* Az = A + (size_t)z * sAz;
    const short* Bz = B + (size_t)z * sBz;
    TOUT* Cz = C + (size_t)z * sCz;

    int Klen = K;
    if (MODE == 2) Klen = min(K, (by + 1) * 256);
    const int NT = Klen >> 5;

    f32x4 acc[8][4];
    #pragma unroll
    for (int i = 0; i < 8; i++)
      #pragma unroll
      for (int j = 0; j < 4; j++) acc[i][j] = (f32x4){0.f, 0.f, 0.f, 0.f};

    auto STAGE_A = [&](int kt) {
      const int buf = kt % 3, k0 = kt * 32;
      #pragma unroll
      for (int j = 0; j < 2; j++) {
        const short* pa;
        if constexpr (MODE == 2)
          pa = Az + (size_t)(tri_by + (k0 >> 8)) * 65536 + (size_t)srow[j] * 256 + (k0 & 255) + scol[j];
        else
          pa = Az + (size_t)(by * 256 + srow[j]) * lda + k0 + scol[j];
        GLDS(pa, (char*)&As[buf][0] + j * 8192 + wave * 1024);
      }
    };
    auto STAGE_B = [&](int kt) {
      const int buf = kt % 3, k0 = kt * 32;
      #pragma unroll
      for (int j = 0; j < 2; j++) {
        const short* pb = Bz + (size_t)(bx * 256 + srow[j]) * ldb + k0 + scol[j];
        GLDS(pb, (char*)&Bs[buf][0] + j * 8192 + wave * 1024);
      }
    };

    STAGE_A(0); STAGE_B(0);
    STAGE_A(1); STAGE_B(1);
    asm volatile("s_waitcnt vmcnt(4)\ns_barrier" ::: "memory");

    for (int kt = 0; kt < NT; kt++) {
      const short* as = &As[kt % 3][0];
      const short* bs = &Bs[kt % 3][0];
      short8 af[4], bfr[4];

      // ---- phase A: frags (m0-3) x (n0-3) ----
      #pragma unroll
      for (int n = 0; n < 4; n++) bfr[n] = *(const short8*)&bs[(brow + n * 16) * 32 + koff];
      #pragma unroll
      for (int m = 0; m < 4; m++) af[m] = *(const short8*)&as[(arow + m * 16) * 32 + koff];
      if (kt + 2 < NT) STAGE_A(kt + 2);
      __builtin_amdgcn_s_barrier();
      asm volatile("s_waitcnt lgkmcnt(0)" ::: "memory");
      __builtin_amdgcn_sched_barrier(0);
      __builtin_amdgcn_s_setprio(1);
      #pragma unroll
      for (int m = 0; m < 4; m++)
        #pragma unroll
        for (int n = 0; n < 4; n++)
          acc[m][n] = __builtin_amdgcn_mfma_f32_16x16x32_bf16(af[m], bfr[n], acc[m][n], 0, 0, 0);
      __builtin_amdgcn_s_setprio(0);
      __builtin_amdgcn_sched_barrier(0);

      // ---- phase B: frags (m4-7) x (n0-3), B held in regs ----
      #pragma unroll
      for (int m = 0; m < 4; m++) af[m] = *(const short8*)&as[(arow + (m + 4) * 16) * 32 + koff];
      if (kt + 2 < NT) STAGE_B(kt + 2);
      __builtin_amdgcn_s_barrier();
      asm volatile("s_waitcnt lgkmcnt(0)" ::: "memory");
      __builtin_amdgcn_sched_barrier(0);
      __builtin_amdgcn_s_setprio(1);
      #pragma unroll
      for (int m = 0; m < 4; m++)
        #pragma unroll
        for (int n = 0; n < 4; n++)
          acc[m + 4][n] = __builtin_amdgcn_mfma_f32_16x16x32_bf16(af[m], bfr[n], acc[m + 4][n], 0, 0, 0);
      __builtin_amdgcn_s_setprio(0);
      __builtin_amdgcn_sched_barrier(0);

      if (kt + 2 < NT)      asm volatile("s_waitcnt vmcnt(4)\ns_barrier" ::: "memory");
      else if (kt + 1 < NT) asm volatile("s_waitcnt vmcnt(0)\ns_barrier" ::: "memory");
    }

    // C/D layout per frag: col = lane&15, row = (lane>>4)*4 + reg (m89)
    #pragma unroll
    for (int m = 0; m < 8; m++)
      #pragma unroll
      for (int n = 0; n < 4; n++) {
        int col_l = wn * 64 + n * 16 + fr;
        #pragma unroll
        for (int r = 0; r < 4; r++) {
          int row_l = wm * 128 + m * 16 + kh * 4 + r;
          if constexpr (MODE == 1)
            store_out(Cz, (size_t)(tri_by + bx) * 65536 + (size_t)row_l * 256 + col_l,
                      acc[m][n][r] * scale);
          else
            store_out(Cz, (size_t)(by * 256 + row_l) * ldc + bx * 256 + col_l,
                      acc[m][n][r] * scale);
        }
      }

    __syncthreads();   // protect s_tile + LDS before next claim
  }
}

// fp32 -> bf16 elementwise convert with scale, 8 elems/thread/iter
__global__ __launch_bounds__(256) void cvt_bf16(
    const float* __restrict__ in, bf16* __restrict__ out, int n, float scale)
{
  for (int i = (blockIdx.x * 256 + threadIdx.x) * 8; i < n; i += gridDim.x * 2048) {
    f32x4 v0 = *(const f32x4*)&in[i];
    f32x4 v1 = *(const f32x4*)&in[i + 4];
    short8 o = { f2bfbits(v0[0] * scale), f2bfbits(v0[1] * scale),
                 f2bfbits(v0[2] * scale), f2bfbits(v0[3] * scale),
                 f2bfbits(v1[0] * scale), f2bfbits(v1[1] * scale),
                 f2bfbits(v1[2] * scale), f2bfbits(v1[3] * scale) };
    *(short8*)&out[i] = o;
  }
}

// In-place softmax on 256-packed block-triangular bf16 scores.
__global__ __launch_bounds__(256) void softmax_causal_packed(short* SP, int T)
{
  __shared__ float rowv[4096];
  __shared__ float red[4];
  const int r = blockIdx.x;
  const int z = blockIdx.y;
  const int rb = r >> 8, rl = r & 255;
  const size_t tri = (size_t)((rb * (rb + 1)) >> 1);
  short* base = SP + (size_t)z * 136 * 65536;
  const int L = r + 1;
  const int kend = (rb + 1) * 256;
  const int t = threadIdx.x;

  float lmax = -3.0e38f;
  for (int i = t * 8; i < kend; i += 2048) {
    short8 s = *(const short8*)(base + (tri + (i >> 8)) * 65536 + (size_t)rl * 256 + (i & 255));
    #pragma unroll
    for (int j = 0; j < 8; j++) {
      float v = bf2f(s[j]);
      rowv[i + j] = v;
      if (i + j < L) lmax = fmaxf(lmax, v);
    }
  }
  #pragma unroll
  for (int o = 32; o > 0; o >>= 1) lmax = fmaxf(lmax, __shfl_down(lmax, o));
  if ((t & 63) == 0) red[t >> 6] = lmax;
  __syncthreads();
  const float m = fmaxf(fmaxf(red[0], red[1]), fmaxf(red[2], red[3]));
  __syncthreads();

  float lsum = 0.f;
  for (int i = t; i < kend; i += 256) {
    float e = (i < L) ? __expf(rowv[i] - m) : 0.f;
    rowv[i] = e;
    lsum += e;
  }
  #pragma unroll
  for (int o = 32; o > 0; o >>= 1) lsum += __shfl_down(lsum, o);
  if ((t & 63) == 0) red[t >> 6] = lsum;
  __syncthreads();
  const float inv = 1.f / (red[0] + red[1] + red[2] + red[3]);

  for (int i = t * 8; i < kend; i += 2048) {
    short8 o;
    #pragma unroll
    for (int j = 0; j < 8; j++) o[j] = f2bfbits(rowv[i + j] * inv);
    *(short8*)(base + (tri + (i >> 8)) * 65536 + (size_t)rl * 256 + (i & 255)) = o;
  }
}

extern "C" void kernel_launch(void* const* d_in, const int* in_sizes, int n_in,
                              void* d_out, int out_size, void* d_ws, size_t ws_size,
                              hipStream_t stream) {
  (void)in_sizes; (void)n_in; (void)out_size; (void)ws_size;
  const float* X  = (const float*)d_in[0];   // (B,T,E)
  const float* Wq = (const float*)d_in[1];   // (A,E)
  const float* Wk = (const float*)d_in[2];
  const float* Wv = (const float*)d_in[3];
  float* Out = (float*)d_out;                // (B,T,A) fp32

  const int Bn = 4, T = 4096, E = 1024, Ad = 1024;
  const int M = Bn * T;  // 16384

  // workspace (peak ~180 MiB):
  //  [0,64Mi)   QKb; [64,96Mi) Vt; [96,128Mi) Xb (dead after proj);
  //  [128,134Mi) Wqk+Wvb (dead after proj); [96Mi,+71.3MB) SP (aliases Xb/W);
  //  [180Mi) qctr: 4 x 16 ints (XCC queue counters, zeroed per launch)
  char* ws = (char*)d_ws;
  short* QKb = (short*)ws;
  short* Vt  = (short*)(ws + 67108864);
  short* Xb  = (short*)(ws + 100663296);
  short* Wqk = (short*)(ws + 134217728);
  short* Wvb = (short*)(ws + 138412032);
  short* SP  = (short*)(ws + 100663296);
  int*  qctr = (int*)(ws + 188743680);

  dim3 blk(256), blk5(512);
  const float qscale = 0.03125f;  // 1/sqrt(1024)
  const size_t SPz = (size_t)136 * 65536;

  hipMemsetAsync(qctr, 0, 4 * 16 * sizeof(int), stream);

  // one-time bf16 conversions (scale folded into Wq)
  cvt_bf16<<<dim3(8192), blk, 0, stream>>>(X, (bf16*)Xb, M * E, 1.0f);
  cvt_bf16<<<dim3(512),  blk, 0, stream>>>(Wq, (bf16*)Wqk, Ad * E, qscale);
  cvt_bf16<<<dim3(512),  blk, 0, stream>>>(Wk, (bf16*)(Wqk + (size_t)Ad * E), Ad * E, 1.0f);
  cvt_bf16<<<dim3(512),  blk, 0, stream>>>(Wv, (bf16*)Wvb, Ad * E, 1.0f);

  // fused Q|K projection: QKb (M x 2048) = Xb . Wqk^T   [512 tiles]
  gemm256<bf16, 0><<<dim3(512), blk5, 0, stream>>>(
      Xb, E, 0, Wqk, E, 0, (bf16*)QKb, 2048, 0, E, 1.0f, qctr + 0);
  // all-batch V^T: Vt (Ad x M) = Wvb . Xb^T             [256 tiles]
  gemm256<bf16, 3><<<dim3(256), blk5, 0, stream>>>(
      Wvb, E, 0, Xb, E, 0, (bf16*)Vt, M, 0, E, 1.0f, qctr + 16);

  // S (256-packed, all batches): S = Q.K^T              [544 tri-tiles]
  gemm256<bf16, 1><<<dim3(544), blk5, 0, stream>>>(
      QKb, 2048, (size_t)T * 2048,
      QKb + 1024, 2048, (size_t)T * 2048,
      (bf16*)SP, 256, SPz, Ad, 1.0f, qctr + 32);

  // in-place softmax on packed scores (all batches)
  softmax_causal_packed<<<dim3(T, Bn), blk, 0, stream>>>(SP, T);

  // O = P.V (256-packed P; causal K-limit)              [256 tiles, paired]
  gemm256<float, 2><<<dim3(256), blk5, 0, stream>>>(
      SP, 256, SPz,
      Vt, M, (size_t)T,
      Out, Ad, (size_t)T * Ad, T, 1.0f, qctr + 48);
}

// Round 12
// 447.213 us; speedup vs baseline: 1.0838x; 1.0838x over previous
//
#include <hip/hip_runtime.h>
#include <hip/hip_bf16.h>

using bf16 = __hip_bfloat16;

typedef __attribute__((ext_vector_type(4))) float f32x4;
typedef __attribute__((ext_vector_type(8))) short short8;

typedef const void __attribute__((address_space(1)))* gas1_t;
typedef void __attribute__((address_space(3)))* las3_t;
#define GLDS(gp, lp) __builtin_amdgcn_global_load_lds((gas1_t)(gp), (las3_t)(lp), 16, 0, 0)

__device__ inline short f2bfbits(float f) {
  union { bf16 h; short s; } u;
  u.h = __float2bfloat16(f);
  return u.s;
}
__device__ inline float bf2f(short u) {
  unsigned x = ((unsigned)(unsigned short)u) << 16;
  float f; __builtin_memcpy(&f, &x, 4); return f;
}

__device__ inline void store_out(float* C, size_t idx, float v) { C[idx] = v; }
__device__ inline void store_out(bf16* C, size_t idx, float v) { C[idx] = __float2bfloat16(v); }

// ---------------------------------------------------------------------------
// 128x128 tile GEMM, BK=32, 256 thr. ROUND-3 loop verbatim (measured best:
// 108us/640TF QKproj): single LDS buffer, plain __syncthreads, gload_lds,
// compiler-scheduled waits, NO inline asm / setprio / sched_barrier (m141:
// order-pinning regresses). Only addition: zero-cost chunk-XOR LDS swizzle
// (16B chunks permuted WITHIN a 64B line -> same cachelines, conflicts -> 0).
// C[m][n] = scale * sum_k A[m][k]*B[n][k]  (row-major operands, B^T layout)
// MODE 0: plain, identity raster (measured-best L2 behavior: FETCH 137MB).
// MODE 1: causal S -> triangular grid (blockIdx.x = tri(by)+bx), C to PACKED
//         128-block-triangular bf16: block (by,bx) at (tri(by)+bx)*16384.
// MODE 2: PV -> A is packed P, K limited to (by+1)*128; paired 1-D decode
//         (co-resident blocks get by and 31-by: equal causal work per CU).
// ---------------------------------------------------------------------------
template<typename TOUT, int MODE>
__global__ __launch_bounds__(256) void gemm_bt(
    const short* __restrict__ A, int lda, size_t sAz,
    const short* __restrict__ B, int ldb, size_t sBz,
    TOUT* __restrict__ C, int ldc, size_t sCz,
    int K, float scale)
{
  int bx, by, z;
  if constexpr (MODE == 1) {
    const int i = blockIdx.x;
    by = (int)((__builtin_sqrtf(8.f * (float)i + 1.f) - 1.f) * 0.5f);
    if (((by * (by + 1)) >> 1) > i) by--;
    else if ((((by + 1) * (by + 2)) >> 1) <= i) by++;
    bx = i - ((by * (by + 1)) >> 1);
    z = blockIdx.z;
  } else if constexpr (MODE == 2) {
    // 1024 = 8(bx) x 32(by) x 4(z); co-resident blocks pair by with 31-by
    const int w = blockIdx.x;
    const int c = w & 255, k = w >> 8;
    bx = c & 7;
    const int g = c >> 3;
    by = (k & 1) ? 31 - g : g;
    z = ((k & 1) << 1) | (k >> 1);
  } else {
    bx = blockIdx.x; by = blockIdx.y; z = blockIdx.z;
  }
  const int tri_by = (by * (by + 1)) >> 1;

  A += (size_t)z * sAz;
  B += (size_t)z * sBz;
  C += (size_t)z * sCz;

  int Klen = K;
  if (MODE == 2) Klen = min(K, (by + 1) * 128);

  __shared__ short a_lds[128 * 32];
  __shared__ short b_lds[128 * 32];

  const int t = threadIdx.x;
  const int lane = t & 63;
  const int wave = t >> 6;
  const int wm = wave >> 1, wn = wave & 1;
  const int fr = lane & 15, kh = lane >> 4;
  const int koff = ((kh ^ ((fr >> 1) & 3)) << 3);   // swizzled 8-short chunk

  f32x4 acc[4][4];
  #pragma unroll
  for (int i = 0; i < 4; i++)
    #pragma unroll
    for (int j = 0; j < 4; j++) acc[i][j] = (f32x4){0.f, 0.f, 0.f, 0.f};

  for (int k0 = 0; k0 < Klen; k0 += 32) {
    #pragma unroll
    for (int i = 0; i < 2; i++) {
      int e = i * 256 + t;
      int row = e >> 2, c = e & 3;
      int sc = ((c ^ ((row >> 1) & 3)) << 3);   // pre-swizzled global chunk
      const short* pa;
      if constexpr (MODE == 2)
        pa = A + ((size_t)(tri_by + (k0 >> 7))) * 16384 + (size_t)row * 128 + (k0 & 127) + sc;
      else
        pa = A + (size_t)(by * 128 + row) * lda + k0 + sc;
      const short* pb = B + (size_t)(bx * 128 + row) * ldb + k0 + sc;
      GLDS(pa, (char*)a_lds + i * 4096 + wave * 1024);
      GLDS(pb, (char*)b_lds + i * 4096 + wave * 1024);
    }
    __syncthreads();   // compiler drains vmcnt before s_barrier

    short8 af[4], bfr[4];
    #pragma unroll
    for (int m = 0; m < 4; m++)
      af[m] = *(const short8*)&a_lds[(wm * 64 + m * 16 + fr) * 32 + koff];
    #pragma unroll
    for (int n = 0; n < 4; n++)
      bfr[n] = *(const short8*)&b_lds[(wn * 64 + n * 16 + fr) * 32 + koff];
    #pragma unroll
    for (int m = 0; m < 4; m++)
      #pragma unroll
      for (int n = 0; n < 4; n++)
        acc[m][n] = __builtin_amdgcn_mfma_f32_16x16x32_bf16(af[m], bfr[n], acc[m][n], 0, 0, 0);
    __syncthreads();
  }

  // C/D layout per frag: col = lane&15, row = (lane>>4)*4 + reg (m89-verified)
  #pragma unroll
  for (int m = 0; m < 4; m++)
    #pragma unroll
    for (int n = 0; n < 4; n++) {
      int col_l = wn * 64 + n * 16 + fr;
      #pragma unroll
      for (int r = 0; r < 4; r++) {
        int row_l = wm * 64 + m * 16 + kh * 4 + r;
        if constexpr (MODE == 1)
          store_out(C, (size_t)(tri_by + bx) * 16384 + (size_t)row_l * 128 + col_l,
                    acc[m][n][r] * scale);
        else
          store_out(C, (size_t)(by * 128 + row_l) * ldc + bx * 128 + col_l,
                    acc[m][n][r] * scale);
      }
    }
}

// fp32 -> bf16 elementwise convert with scale, 8 elems/thread/iter
__global__ __launch_bounds__(256) void cvt_bf16(
    const float* __restrict__ in, bf16* __restrict__ out, int n, float scale)
{
  for (int i = (blockIdx.x * 256 + threadIdx.x) * 8; i < n; i += gridDim.x * 2048) {
    f32x4 v0 = *(const f32x4*)&in[i];
    f32x4 v1 = *(const f32x4*)&in[i + 4];
    short8 o = { f2bfbits(v0[0] * scale), f2bfbits(v0[1] * scale),
                 f2bfbits(v0[2] * scale), f2bfbits(v0[3] * scale),
                 f2bfbits(v1[0] * scale), f2bfbits(v1[1] * scale),
                 f2bfbits(v1[2] * scale), f2bfbits(v1[3] * scale) };
    *(short8*)&out[i] = o;
  }
}

// In-place softmax on 128-packed block-triangular bf16 scores.
__global__ __launch_bounds__(256) void softmax_causal_packed(short* SP, int T)
{
  __shared__ float rowv[4096];
  __shared__ float red[4];
  const int r = blockIdx.x;
  const int z = blockIdx.y;
  const int rb = r >> 7, rl = r & 127;
  const size_t tri = (size_t)((rb * (rb + 1)) >> 1);
  short* base = SP + (size_t)z * 528 * 16384;
  const int L = r + 1;
  const int kend = (rb + 1) * 128;
  const int t = threadIdx.x;

  float lmax = -3.0e38f;
  for (int i = t * 8; i < kend; i += 2048) {
    short8 s = *(const short8*)(base + (tri + (i >> 7)) * 16384 + (size_t)rl * 128 + (i & 127));
    #pragma unroll
    for (int j = 0; j < 8; j++) {
      float v = bf2f(s[j]);
      rowv[i + j] = v;
      if (i + j < L) lmax = fmaxf(lmax, v);
    }
  }
  #pragma unroll
  for (int o = 32; o > 0; o >>= 1) lmax = fmaxf(lmax, __shfl_down(lmax, o));
  if ((t & 63) == 0) red[t >> 6] = lmax;
  __syncthreads();
  const float m = fmaxf(fmaxf(red[0], red[1]), fmaxf(red[2], red[3]));
  __syncthreads();

  float lsum = 0.f;
  for (int i = t; i < kend; i += 256) {
    float e = (i < L) ? __expf(rowv[i] - m) : 0.f;
    rowv[i] = e;
    lsum += e;
  }
  #pragma unroll
  for (int o = 32; o > 0; o >>= 1) lsum += __shfl_down(lsum, o);
  if ((t & 63) == 0) red[t >> 6] = lsum;
  __syncthreads();
  const float inv = 1.f / (red[0] + red[1] + red[2] + red[3]);

  for (int i = t * 8; i < kend; i += 2048) {
    short8 o;
    #pragma unroll
    for (int j = 0; j < 8; j++) o[j] = f2bfbits(rowv[i + j] * inv);
    *(short8*)(base + (tri + (i >> 7)) * 16384 + (size_t)rl * 128 + (i & 127)) = o;
  }
}

extern "C" void kernel_launch(void* const* d_in, const int* in_sizes, int n_in,
                              void* d_out, int out_size, void* d_ws, size_t ws_size,
                              hipStream_t stream) {
  (void)in_sizes; (void)n_in; (void)out_size; (void)ws_size;
  const float* X  = (const float*)d_in[0];   // (B,T,E)
  const float* Wq = (const float*)d_in[1];   // (A,E)
  const float* Wk = (const float*)d_in[2];
  const float* Wv = (const float*)d_in[3];
  float* Out = (float*)d_out;                // (B,T,A) fp32

  const int Bn = 4, T = 4096, E = 1024, Ad = 1024;
  const int M = Bn * T;  // 16384

  // workspace (peak ~162 MiB):
  //  [0,64Mi)   QKb : M x 2048 bf16 (Q | K interleaved per row)
  //  [64,96Mi)  Vt  : Ad x M bf16 (all-batch V^T; batch b at column b*T)
  //  [96,128Mi) Xb  : M x E bf16 (dead after projections)
  //  [128,134Mi) W  : Wqk (2048xE) + Wvb (AdxE) bf16 (dead after projections)
  //  [96Mi, +69.2MB) SP : 128-packed block-tri bf16, 4 x 528 x 128x128
  char* ws = (char*)d_ws;
  short* QKb = (short*)ws;
  short* Vt  = (short*)(ws + 67108864);
  short* Xb  = (short*)(ws + 100663296);
  short* Wqk = (short*)(ws + 134217728);
  short* Wvb = (short*)(ws + 138412032);
  short* SP  = (short*)(ws + 100663296);   // aliases Xb/W after projections

  dim3 blk(256);
  const float qscale = 0.03125f;  // 1/sqrt(1024)
  const size_t SPz = (size_t)528 * 16384;

  // one-time bf16 conversions (scale folded into Wq)
  cvt_bf16<<<dim3(8192), blk, 0, stream>>>(X, (bf16*)Xb, M * E, 1.0f);
  cvt_bf16<<<dim3(512),  blk, 0, stream>>>(Wq, (bf16*)Wqk, Ad * E, qscale);
  cvt_bf16<<<dim3(512),  blk, 0, stream>>>(Wk, (bf16*)(Wqk + (size_t)Ad * E), Ad * E, 1.0f);
  cvt_bf16<<<dim3(512),  blk, 0, stream>>>(Wv, (bf16*)Wvb, Ad * E, 1.0f);

  // fused Q|K projection: QKb (M x 2048) = Xb . Wqk^T  [identity raster]
  gemm_bt<bf16, 0><<<dim3(2048 / 128, M / 128), blk, 0, stream>>>(
      Xb, E, 0, Wqk, E, 0, (bf16*)QKb, 2048, 0, E, 1.0f);
  // all-batch V^T: Vt (Ad x M) = Wvb . Xb^T  [identity raster]
  gemm_bt<bf16, 0><<<dim3(M / 128, Ad / 128), blk, 0, stream>>>(
      Wvb, E, 0, Xb, E, 0, (bf16*)Vt, M, 0, E, 1.0f);

  // S (128-packed, all batches): S = Q.K^T, triangular grid (528/batch)
  gemm_bt<bf16, 1><<<dim3(528, 1, Bn), blk, 0, stream>>>(
      QKb, 2048, (size_t)T * 2048,
      QKb + 1024, 2048, (size_t)T * 2048,
      (bf16*)SP, 128, SPz, Ad, 1.0f);

  // in-place softmax on packed scores (all batches)
  softmax_causal_packed<<<dim3(T, Bn), blk, 0, stream>>>(SP, T);

  // O = P.V (packed P as A; 1-D paired grid: 8 bx x 32 by x 4 z)
  gemm_bt<float, 2><<<dim3(1024), blk, 0, stream>>>(
      SP, 128, SPz,
      Vt, M, (size_t)T,
      Out, Ad, (size_t)T * Ad, T, 1.0f);
}